// Round 1
// baseline (132.586 us; speedup 1.0000x reference)
//
#include <hip/hip_runtime.h>
#include <math.h>

// Hausdorff distance, B=16, N=4096, D=3, fp32.
// loss1 = max_gt min_pred ||p-g||^2 ; loss2 = max_pred min_gt ||p-g||^2
// out[b] = 0.5*(loss1+loss2)
//
// Strategy: per-direction nearest-neighbor scan. Each block owns
// (home-tile of 1024 pts, opponent-chunk of 1024 pts, batch, direction).
// Opponent points staged in LDS as float4 (broadcast ds_read_b128 in inner
// loop); M=4 home points per thread amortize each LDS read over 28 VALU
// instructions -> VALU-bound. Partial mins combined across opponent chunks
// via atomicMin on float bits (valid for non-negative floats). Final kernel
// reduces max per (dir, batch) and averages.

#define NPTS 4096
#define NB 16
#define TPB 256
#define M 4                 // home points per thread
#define SPLIT 4             // opponent chunks (for occupancy)
#define HT (TPB * M)        // 1024 home points per block
#define OC (NPTS / SPLIT)   // 1024 opponent points per chunk
#define NHT (NPTS / HT)     // 4 home tiles

__global__ __launch_bounds__(TPB) void init_ws_kernel(unsigned int* ws) {
    ws[(size_t)blockIdx.x * TPB + threadIdx.x] = 0x7F800000u;  // +inf
}

__global__ __launch_bounds__(TPB) void haus_scan_kernel(
        const float* __restrict__ preds, const float* __restrict__ gts,
        unsigned int* __restrict__ wsmin) {
    const int ht  = blockIdx.x & (NHT - 1);   // home tile index
    const int oc  = blockIdx.x >> 2;          // opponent chunk index (NHT==4)
    const int b   = blockIdx.y;
    const int dir = blockIdx.z;               // 0: home=gts scan preds; 1: home=preds scan gts
    const int t   = threadIdx.x;

    const float* home = (dir == 0) ? gts : preds;
    const float* opp  = (dir == 0) ? preds : gts;
    const float* hb = home + (size_t)b * NPTS * 3;
    const float* ob = opp  + (size_t)b * NPTS * 3;

    float px[M], py[M], pz[M], best[M];
#pragma unroll
    for (int k = 0; k < M; ++k) {
        int hi = ht * HT + k * TPB + t;
        px[k] = hb[hi * 3 + 0];
        py[k] = hb[hi * 3 + 1];
        pz[k] = hb[hi * 3 + 2];
        best[k] = INFINITY;
    }

    __shared__ float4 q[TPB];
    const int base = oc * OC;
    for (int tb = 0; tb < OC; tb += TPB) {
        const float* src = ob + (size_t)(base + tb) * 3;
        float qx = src[t * 3 + 0];
        float qy = src[t * 3 + 1];
        float qz = src[t * 3 + 2];
        __syncthreads();                       // protect q from previous round's readers
        q[t] = make_float4(qx, qy, qz, 0.0f);
        __syncthreads();
#pragma unroll 4
        for (int j = 0; j < TPB; ++j) {
            float4 qq = q[j];                  // wave-uniform address -> LDS broadcast
#pragma unroll
            for (int k = 0; k < M; ++k) {
                float dx = px[k] - qq.x;
                float dy = py[k] - qq.y;
                float dz = pz[k] - qq.z;
                float d = fmaf(dx, dx, fmaf(dy, dy, dz * dz));
                best[k] = fminf(best[k], d);
            }
        }
    }

    unsigned int* slot = wsmin + ((size_t)dir * NB + b) * NPTS + ht * HT;
#pragma unroll
    for (int k = 0; k < M; ++k) {
        // distances are >= 0 so uint-bit ordering == float ordering
        atomicMin(slot + k * TPB + t, __float_as_uint(best[k]));
    }
}

__global__ __launch_bounds__(TPB) void haus_final_kernel(
        const unsigned int* __restrict__ wsmin, float* __restrict__ out) {
    const int b = blockIdx.x;
    const int t = threadIdx.x;
    float m1 = -INFINITY, m2 = -INFINITY;
    for (int j = t; j < NPTS; j += TPB) {
        m1 = fmaxf(m1, __uint_as_float(wsmin[((size_t)0 * NB + b) * NPTS + j]));
        m2 = fmaxf(m2, __uint_as_float(wsmin[((size_t)1 * NB + b) * NPTS + j]));
    }
#pragma unroll
    for (int off = 32; off > 0; off >>= 1) {
        m1 = fmaxf(m1, __shfl_down(m1, off, 64));
        m2 = fmaxf(m2, __shfl_down(m2, off, 64));
    }
    __shared__ float s1[4], s2[4];
    if ((t & 63) == 0) { s1[t >> 6] = m1; s2[t >> 6] = m2; }
    __syncthreads();
    if (t == 0) {
        float a = fmaxf(fmaxf(s1[0], s1[1]), fmaxf(s1[2], s1[3]));
        float c = fmaxf(fmaxf(s2[0], s2[1]), fmaxf(s2[2], s2[3]));
        out[b] = 0.5f * (a + c);
    }
}

extern "C" void kernel_launch(void* const* d_in, const int* in_sizes, int n_in,
                              void* d_out, int out_size, void* d_ws, size_t ws_size,
                              hipStream_t stream) {
    const float* preds = (const float*)d_in[0];
    const float* gts   = (const float*)d_in[1];
    float* out = (float*)d_out;
    unsigned int* wsmin = (unsigned int*)d_ws;   // 2*16*4096 uints = 512 KB

    // init per-home-point min slots to +inf (ws is poisoned to 0xAA)
    init_ws_kernel<<<dim3(2 * NB * NPTS / TPB), dim3(TPB), 0, stream>>>(wsmin);

    // main NN scan: grid.x packs (home tile, opponent chunk)
    haus_scan_kernel<<<dim3(NHT * SPLIT, NB, 2), dim3(TPB), 0, stream>>>(preds, gts, wsmin);

    // per-batch max over mins + average of both directions
    haus_final_kernel<<<dim3(NB), dim3(TPB), 0, stream>>>(wsmin, out);
}

// Round 2
// 97.607 us; speedup vs baseline: 1.3584x; 1.3584x over previous
//
#include <hip/hip_runtime.h>
#include <math.h>

// Hausdorff distance, B=16, N=4096, D=3, fp32.
// out[b] = 0.5*(max_gt min_pred d + max_pred min_gt d), d = ||p-q||^2
//
// R2: half-distance dot formulation. Store opponent point as float4
// (qx,qy,qz, hq=|q|^2/2) in LDS; per pair acc = hq - p.q via 3 FMAs
// (free neg modifiers) + 1 min = 4 VALU/pair (was 7). Home-point term
// hp=|p|^2/2 folded in once after the scan; clamp at 0 so uint-bit
// atomicMin ordering is exact. M=8 home pts/thread -> one ds_read_b128
// per 32 VALU (LDS pipe no longer co-saturated). SPLIT=16 -> 1024 blocks
// = 4 blocks/CU = 16 waves/CU. Whole opponent chunk staged once -> one
// barrier per block, none in the hot loop.

#define NPTS 4096
#define NB 16
#define TPB 256
#define M 8                  // home points per thread
#define SPLIT 16             // opponent chunks
#define HT (TPB * M)         // 2048 home points per block
#define OC (NPTS / SPLIT)    // 256 opponent points per chunk
#define NHT (NPTS / HT)      // 2 home tiles

__global__ __launch_bounds__(TPB) void init_ws_kernel(unsigned int* ws) {
    ws[(size_t)blockIdx.x * TPB + threadIdx.x] = 0x7F800000u;  // +inf
}

__global__ __launch_bounds__(TPB) void haus_scan_kernel(
        const float* __restrict__ preds, const float* __restrict__ gts,
        unsigned int* __restrict__ wsmin) {
    const int ht  = blockIdx.x & (NHT - 1);    // home tile index
    const int oc  = blockIdx.x >> 1;           // opponent chunk index (NHT==2)
    const int b   = blockIdx.y;
    const int dir = blockIdx.z;                // 0: home=gts scan preds; 1: home=preds scan gts
    const int t   = threadIdx.x;

    const float* home = (dir == 0) ? gts : preds;
    const float* opp  = (dir == 0) ? preds : gts;
    const float* hb = home + (size_t)b * NPTS * 3;
    const float* ob = opp  + (size_t)b * NPTS * 3;

    // stage opponent chunk: (qx,qy,qz, |q|^2/2)
    __shared__ float4 q[OC];
    {
        const float* src = ob + (size_t)(oc * OC + t) * 3;
        float qx = src[0], qy = src[1], qz = src[2];
        float hq = 0.5f * fmaf(qx, qx, fmaf(qy, qy, qz * qz));
        q[t] = make_float4(qx, qy, qz, hq);
    }

    float px[M], py[M], pz[M], hp[M], best[M];
#pragma unroll
    for (int k = 0; k < M; ++k) {
        int hi = ht * HT + k * TPB + t;
        px[k] = hb[hi * 3 + 0];
        py[k] = hb[hi * 3 + 1];
        pz[k] = hb[hi * 3 + 2];
        hp[k] = 0.5f * fmaf(px[k], px[k], fmaf(py[k], py[k], pz[k] * pz[k]));
        best[k] = INFINITY;
    }

    __syncthreads();

#pragma unroll 4
    for (int j = 0; j < OC; ++j) {
        float4 qq = q[j];                      // wave-uniform -> LDS broadcast
#pragma unroll
        for (int k = 0; k < M; ++k) {
            // acc = hq - p.q   (half squared distance minus hp)
            float acc = fmaf(-px[k], qq.x, qq.w);
            acc = fmaf(-py[k], qq.y, acc);
            acc = fmaf(-pz[k], qq.z, acc);
            best[k] = fminf(best[k], acc);
        }
    }

    unsigned int* slot = wsmin + ((size_t)dir * NB + b) * NPTS + ht * HT;
#pragma unroll
    for (int k = 0; k < M; ++k) {
        // half-distance; clamp >=0 so uint-bit ordering == float ordering
        float d2 = fmaxf(best[k] + hp[k], 0.0f);
        atomicMin(slot + k * TPB + t, __float_as_uint(d2));
    }
}

__global__ __launch_bounds__(TPB) void haus_final_kernel(
        const unsigned int* __restrict__ wsmin, float* __restrict__ out) {
    const int b = blockIdx.x;
    const int t = threadIdx.x;
    const float4* w0 = (const float4*)(wsmin + ((size_t)0 * NB + b) * NPTS);
    const float4* w1 = (const float4*)(wsmin + ((size_t)1 * NB + b) * NPTS);
    float m1 = -INFINITY, m2 = -INFINITY;
#pragma unroll
    for (int r = 0; r < NPTS / 4 / TPB; ++r) {   // 4 float4 per thread
        float4 a = w0[r * TPB + t];
        float4 c = w1[r * TPB + t];
        m1 = fmaxf(fmaxf(fmaxf(a.x, a.y), fmaxf(a.z, a.w)), m1);
        m2 = fmaxf(fmaxf(fmaxf(c.x, c.y), fmaxf(c.z, c.w)), m2);
    }
#pragma unroll
    for (int off = 32; off > 0; off >>= 1) {
        m1 = fmaxf(m1, __shfl_down(m1, off, 64));
        m2 = fmaxf(m2, __shfl_down(m2, off, 64));
    }
    __shared__ float s1[4], s2[4];
    if ((t & 63) == 0) { s1[t >> 6] = m1; s2[t >> 6] = m2; }
    __syncthreads();
    if (t == 0) {
        float a = fmaxf(fmaxf(s1[0], s1[1]), fmaxf(s1[2], s1[3]));
        float c = fmaxf(fmaxf(s2[0], s2[1]), fmaxf(s2[2], s2[3]));
        out[b] = a + c;   // values are d/2, so sum == 0.5*(loss1+loss2)
    }
}

extern "C" void kernel_launch(void* const* d_in, const int* in_sizes, int n_in,
                              void* d_out, int out_size, void* d_ws, size_t ws_size,
                              hipStream_t stream) {
    const float* preds = (const float*)d_in[0];
    const float* gts   = (const float*)d_in[1];
    float* out = (float*)d_out;
    unsigned int* wsmin = (unsigned int*)d_ws;   // 2*16*4096 uints = 512 KB

    init_ws_kernel<<<dim3(2 * NB * NPTS / TPB), dim3(TPB), 0, stream>>>(wsmin);

    haus_scan_kernel<<<dim3(NHT * SPLIT, NB, 2), dim3(TPB), 0, stream>>>(preds, gts, wsmin);

    haus_final_kernel<<<dim3(NB), dim3(TPB), 0, stream>>>(wsmin, out);
}